// Round 21
// baseline (388.064 us; speedup 1.0000x reference)
//
#include <hip/hip_runtime.h>
#include <math.h>

#define H 300
#define NLEAF 4096

typedef unsigned int  uint;
typedef unsigned short ushort;
typedef __attribute__((ext_vector_type(8))) short  short8;
typedef __attribute__((ext_vector_type(4))) float  f32x4;

__device__ __forceinline__ float sigmoidf_(float x) { return 1.0f / (1.0f + expf(-x)); }

__device__ __forceinline__ ushort f2bf(float f)
{
    uint u = __float_as_uint(f);
    u += 0x7FFF + ((u >> 16) & 1);
    return (ushort)(u >> 16);
}
__device__ __forceinline__ uint2 pack4(float4 v)
{
    uint2 w;
    w.x = (uint)f2bf(v.x) | ((uint)f2bf(v.y) << 16);
    w.y = (uint)f2bf(v.z) | ((uint)f2bf(v.w) << 16);
    return w;
}

// ---- per-wave MFMA GEMM: NT 16-wide col-tiles, KSTEPS k-steps of 32 ----
// A in LDS (row stride AS ushorts, 16 rows starting at A_lds). B global
// col-major (col stride KS). A row=lane%16, k=(lane>>4)*8+i; B col=lane%16;
// C/D col=lane&15, row=(lane>>4)*4+reg (m89-verified). Depth-2 prefetch.
template<int NT, int KSTEPS, int AS, int KS>
__device__ __forceinline__ void mfma_gemm(const ushort* A_lds, const ushort* __restrict__ B,
                                          int colT0, int lane, f32x4* acc)
{
    const ushort* Ap = A_lds + (lane & 15) * AS + ((lane >> 4) * 8);
    const ushort* Bp[NT];
    #pragma unroll
    for (int t = 0; t < NT; ++t)
        Bp[t] = B + (long)(colT0 + 16 * t + (lane & 15)) * KS + ((lane >> 4) * 8);

    short8 aA, aB, bA[NT], bB[NT];
    aA = *(const short8*)Ap;
    #pragma unroll
    for (int t = 0; t < NT; ++t) bA[t] = *(const short8*)Bp[t];

    int s = 0;
    #pragma unroll 1
    for (; s + 2 < KSTEPS; s += 2) {
        aB = *(const short8*)(Ap + (s + 1) * 32);
        #pragma unroll
        for (int t = 0; t < NT; ++t) bB[t] = *(const short8*)(Bp[t] + (s + 1) * 32);
        #pragma unroll
        for (int t = 0; t < NT; ++t)
            acc[t] = __builtin_amdgcn_mfma_f32_16x16x32_bf16(aA, bA[t], acc[t], 0, 0, 0);
        aA = *(const short8*)(Ap + (s + 2) * 32);
        #pragma unroll
        for (int t = 0; t < NT; ++t) bA[t] = *(const short8*)(Bp[t] + (s + 2) * 32);
        #pragma unroll
        for (int t = 0; t < NT; ++t)
            acc[t] = __builtin_amdgcn_mfma_f32_16x16x32_bf16(aB, bB[t], acc[t], 0, 0, 0);
    }
    if (KSTEPS - s == 2) {
        aB = *(const short8*)(Ap + (s + 1) * 32);
        #pragma unroll
        for (int t = 0; t < NT; ++t) bB[t] = *(const short8*)(Bp[t] + (s + 1) * 32);
        #pragma unroll
        for (int t = 0; t < NT; ++t)
            acc[t] = __builtin_amdgcn_mfma_f32_16x16x32_bf16(aA, bA[t], acc[t], 0, 0, 0);
        #pragma unroll
        for (int t = 0; t < NT; ++t)
            acc[t] = __builtin_amdgcn_mfma_f32_16x16x32_bf16(aB, bB[t], acc[t], 0, 0, 0);
    } else {
        #pragma unroll
        for (int t = 0; t < NT; ++t)
            acc[t] = __builtin_amdgcn_mfma_f32_16x16x32_bf16(aA, bA[t], acc[t], 0, 0, 0);
    }
}

// ---- merged prep: weight transpose/convert (blocks 0-639) + tag tables (640-699)
__global__ __launch_bounds__(256) void prep_k(
    const float* __restrict__ Wr, const float* __restrict__ Wz,
    const float* __restrict__ Wu, const float* __restrict__ tag_table,
    const float* __restrict__ br, const float* __restrict__ bz,
    ushort* __restrict__ WArz, ushort* __restrict__ WuTp, ushort* __restrict__ WLzu,
    float* __restrict__ tag_r, float* __restrict__ tag_z)
{
    __shared__ float te[50];
    int b = blockIdx.x;
    int tid = threadIdx.x;
    if (b < 640) {
        int c = b;
        int gate = (c >= 320);
        int cc = gate ? c - 320 : c;
        const float* WA = gate ? Wz : Wr;
        for (int r = tid; r < 608; r += 256) {
            float v = 0.f;
            if (cc < 300) {
                if (r < 300) v = WA[(350 + r) * H + cc];
                else if (r >= 304 && r < 604) v = WA[(r + 346) * H + cc];
            }
            WArz[(long)c * 608 + r] = f2bf(v);
        }
        const float* WL = gate ? Wu : Wz;
        for (int r = tid; r < 320; r += 256) {
            float v = (cc < 300 && r < 300) ? WL[r * H + cc] : 0.f;
            WLzu[(long)c * 320 + r] = f2bf(v);
        }
        if (c < 320) {
            for (int r = tid; r < 608; r += 256) {
                float v = 0.f;
                if (c < 300) {
                    if (r < 300) v = Wu[(300 + r) * H + c];
                    else if (r >= 304 && r < 604) v = Wu[(r + 296) * H + c];
                }
                WuTp[(long)c * 608 + r] = f2bf(v);
            }
        }
    } else {
        int t = b - 640;                 // 0..59
        if (tid < 50) te[tid] = tag_table[t * 50 + tid];
        __syncthreads();
        for (int k = tid; k < H; k += 256) {
            float ar = br[k], az = bz[k];
            #pragma unroll 10
            for (int j = 0; j < 50; ++j) {
                float tv = te[j];
                ar = fmaf(tv, Wr[(H + j) * H + k], ar);
                az = fmaf(tv, Wz[(H + j) * H + k], az);
            }
            tag_r[t * H + k] = ar;
            tag_z[t * H + k] = az;
        }
    }
}

// ---- Leaf, MT=32, column-split (4 col-blocks of 80). One kernel:
// z and u share output columns, so z stays in registers per wave.
template<int NT>
__device__ __forceinline__ void leaf_cols(
    const ushort* Arow, const ushort* __restrict__ WLzu, int colT0, int lane,
    int node0, int jrow, const int* __restrict__ tag_ids,
    const float* __restrict__ tag_z, const float* __restrict__ bu,
    float* __restrict__ out)
{
    f32x4 accZ[NT], accU[NT];
    #pragma unroll
    for (int t = 0; t < NT; ++t) { accZ[t] = (f32x4)(0.f); accU[t] = (f32x4)(0.f); }
    mfma_gemm<NT, 10, 328, 320>(Arow, WLzu, colT0, lane, accZ);
    mfma_gemm<NT, 10, 328, 320>(Arow, WLzu, 320 + colT0, lane, accU);
    int tg[4];
    #pragma unroll
    for (int q = 0; q < 4; ++q) tg[q] = tag_ids[node0 + jrow + q];
    #pragma unroll
    for (int t = 0; t < NT; ++t) {
        int c = colT0 + t * 16 + (lane & 15);
        #pragma unroll
        for (int q = 0; q < 4; ++q) {
            if (c < 300) {
                float z = sigmoidf_(accZ[t][q] + tag_z[tg[q] * H + c]);
                float u = tanhf(accU[t][q] + bu[c]);
                out[(long)(node0 + jrow + q) * H + c] = (1.f - z) * u;
            }
        }
    }
}

__global__ __launch_bounds__(256, 1) void leaf32_k(
    const int* __restrict__ word_ids, const int* __restrict__ tag_ids,
    const float* __restrict__ word_table, const ushort* __restrict__ WLzu,
    const float* __restrict__ bu, const float* __restrict__ tag_z,
    float* __restrict__ out)
{
    __shared__ ushort Abf[32 * 328];
    int tid = threadIdx.x;
    int mt = blockIdx.x >> 2, cb = blockIdx.x & 3;
    int node0 = mt * 32;

    for (int idx = tid; idx < 32 * 82; idx += 256) {
        int j = idx / 82, q = idx - j * 82;
        char* rowb = (char*)(Abf + j * 328);
        if (q < 75) {
            float4 v = ((const float4*)(word_table + (long)word_ids[node0 + j] * H))[q];
            *(uint2*)(rowb + q * 8) = pack4(v);
        } else {
            *(uint2*)(rowb + q * 8) = make_uint2(0u, 0u);
        }
    }
    __syncthreads();

    int wv = tid >> 6, lane = tid & 63;
    int rt = wv & 1, half = wv >> 1;
    const ushort* Arow = Abf + 16 * rt * 328;
    int jrow = 16 * rt + (lane >> 4) * 4;
    if (half == 0)
        leaf_cols<3>(Arow, WLzu, cb * 80,      lane, node0, jrow, tag_ids, tag_z, bu, out);
    else
        leaf_cols<2>(Arow, WLzu, cb * 80 + 48, lane, node0, jrow, tag_ids, tag_z, bu, out);
}

// ---- Big levels (m >= 256), MT=32, column-split: gates + u kernels ----
template<int NT>
__device__ __forceinline__ void gates_cols(
    const ushort* Arow, const ushort* __restrict__ WArz, int colT0, int lane,
    int node0, int jrow, int off, int prevOff,
    const int* __restrict__ tag_ids, const float* __restrict__ tag_r,
    const float* __restrict__ tag_z, const float* __restrict__ out,
    float* __restrict__ zws, float* __restrict__ Sws, ushort* __restrict__ rxws)
{
    f32x4 acc[NT];
    #pragma unroll
    for (int t = 0; t < NT; ++t) acc[t] = (f32x4)(0.f);
    mfma_gemm<NT, 19, 616, 608>(Arow, WArz, colT0, lane, acc);
    int tg[4];
    #pragma unroll
    for (int q = 0; q < 4; ++q) tg[q] = tag_ids[off + node0 + jrow + q];
    #pragma unroll
    for (int t = 0; t < NT; ++t) {
        int c = colT0 + t * 16 + (lane & 15);
        #pragma unroll
        for (int q = 0; q < 4; ++q) {
            int gn = node0 + jrow + q;
            if (c < 320) {                       // r gate
                if (c < 300) {
                    float r  = sigmoidf_(acc[t][q] + tag_r[tg[q] * H + c]);
                    float lh = out[(long)(prevOff + 2 * gn) * H + c];
                    float rh = out[(long)(prevOff + 2 * gn + 1) * H + c];
                    Sws[gn * 304 + c] = lh + rh;
                    rxws[(long)gn * 608 + c]       = f2bf(r * lh);
                    rxws[(long)gn * 608 + 304 + c] = f2bf(r * rh);
                } else if (c < 304) {
                    rxws[(long)gn * 608 + c]       = 0;
                    rxws[(long)gn * 608 + 304 + c] = 0;
                }
            } else {                             // z gate
                int cz = c - 320;
                if (cz < 300)
                    zws[gn * 304 + cz] = sigmoidf_(acc[t][q] + tag_z[tg[q] * H + cz]);
            }
        }
    }
}

__global__ __launch_bounds__(256, 1) void glevel32_k(
    const int* __restrict__ tag_ids, const ushort* __restrict__ WArz,
    const float* __restrict__ tag_r, const float* __restrict__ tag_z,
    const float* __restrict__ out,
    float* __restrict__ zws, float* __restrict__ Sws, ushort* __restrict__ rxws,
    int off, int prevOff)
{
    __shared__ ushort Abf[32 * 616];
    int tid = threadIdx.x;
    int mt = blockIdx.x >> 3, cb = blockIdx.x & 7;
    int node0 = mt * 32;

    for (int idx = tid; idx < 32 * 154; idx += 256) {
        int j = idx / 154, q = idx - j * 154;
        char* rowb = (char*)(Abf + j * 616);
        if (q < 75) {
            float4 v = ((const float4*)(out + (long)(prevOff + 2 * (node0 + j)) * H))[q];
            *(uint2*)(rowb + q * 8) = pack4(v);
        } else if (q < 150) {
            int qq = q - 75;
            float4 v = ((const float4*)(out + (long)(prevOff + 2 * (node0 + j) + 1) * H))[qq];
            *(uint2*)(rowb + 608 + qq * 8) = pack4(v);
        } else {
            int pb = (q == 150) ? 600 : (1208 + (q - 151) * 8);   // pads 300-303, 604-615
            *(uint2*)(rowb + pb) = make_uint2(0u, 0u);
        }
    }
    __syncthreads();

    int wv = tid >> 6, lane = tid & 63;
    int rt = wv & 1, half = wv >> 1;
    const ushort* Arow = Abf + 16 * rt * 616;
    int jrow = 16 * rt + (lane >> 4) * 4;
    if (half == 0)
        gates_cols<3>(Arow, WArz, cb * 80,      lane, node0, jrow, off, prevOff,
                      tag_ids, tag_r, tag_z, out, zws, Sws, rxws);
    else
        gates_cols<2>(Arow, WArz, cb * 80 + 48, lane, node0, jrow, off, prevOff,
                      tag_ids, tag_r, tag_z, out, zws, Sws, rxws);
}

template<int NT>
__device__ __forceinline__ void u_cols(
    const ushort* Arow, const ushort* __restrict__ WuTp, int colT0, int lane,
    int node0, int jrow, int off, const float* __restrict__ bu,
    const float* __restrict__ zws, const float* __restrict__ Sws,
    float* __restrict__ out, float* __restrict__ dup)
{
    f32x4 acc[NT];
    #pragma unroll
    for (int t = 0; t < NT; ++t) acc[t] = (f32x4)(0.f);
    mfma_gemm<NT, 19, 616, 608>(Arow, WuTp, colT0, lane, acc);
    #pragma unroll
    for (int t = 0; t < NT; ++t) {
        int c = colT0 + t * 16 + (lane & 15);
        #pragma unroll
        for (int q = 0; q < 4; ++q) {
            int gn = node0 + jrow + q;
            if (c < 300) {
                float u = tanhf(acc[t][q] + bu[c]);
                float z = zws[gn * 304 + c];
                float h = z * Sws[gn * 304 + c] + (1.f - z) * u;
                out[(long)(off + gn) * H + c] = h;
                if (dup && gn == 0) dup[c] = h;
            }
        }
    }
}

__global__ __launch_bounds__(256, 1) void ulevel32_k(
    const ushort* __restrict__ WuTp, const float* __restrict__ bu,
    const float* __restrict__ zws, const float* __restrict__ Sws,
    const ushort* __restrict__ rxws,
    float* __restrict__ out, int off)
{
    __shared__ ushort Abf[32 * 616];
    int tid = threadIdx.x;
    int mt = blockIdx.x >> 2, ub = blockIdx.x & 3;
    int node0 = mt * 32;

    for (int idx = tid; idx < 32 * 77; idx += 256) {
        int j = idx / 77, q = idx - j * 77;
        uint4* dst = (uint4*)(Abf + j * 616) + q;
        if (q < 76) *dst = ((const uint4*)(rxws + (long)(node0 + j) * 608))[q];
        else        *dst = make_uint4(0u, 0u, 0u, 0u);
    }
    __syncthreads();

    int wv = tid >> 6, lane = tid & 63;
    int rt = wv & 1, half = wv >> 1;
    const ushort* Arow = Abf + 16 * rt * 616;
    int jrow = 16 * rt + (lane >> 4) * 4;
    if (half == 0)
        u_cols<3>(Arow, WuTp, ub * 80,      lane, node0, jrow, off, bu, zws, Sws, out, nullptr);
    else
        u_cols<2>(Arow, WuTp, ub * 80 + 48, lane, node0, jrow, off, bu, zws, Sws, out, nullptr);
}

// ---- Small levels (m <= 128): per-level 2-kernel column+K-split (MT=16) ----
__global__ __launch_bounds__(256, 1) void split_gates_k(
    const int* __restrict__ tag_ids, const ushort* __restrict__ WArz,
    const float* __restrict__ tag_r, const float* __restrict__ tag_z,
    const float* __restrict__ out,
    float* __restrict__ zws, float* __restrict__ Sws, ushort* __restrict__ rxws,
    int off, int prevOff, int m)
{
    __shared__ ushort Abf[16 * 616];
    __shared__ float pbuf[3][64][20];
    int tid = threadIdx.x;
    int mt = blockIdx.x >> 3, cb = blockIdx.x & 7;
    int node0 = mt * 16;

    for (int idx = tid; idx < 16 * 154; idx += 256) {
        int j = idx / 154, q = idx - j * 154;
        char* rowb = (char*)(Abf + j * 616);
        bool valid = (node0 + j) < m;
        if (q < 75) {
            uint2 w = make_uint2(0u, 0u);
            if (valid) {
                float4 v = ((const float4*)(out + (long)(prevOff + 2 * (node0 + j)) * H))[q];
                w = pack4(v);
            }
            *(uint2*)(rowb + q * 8) = w;
        } else if (q < 150) {
            int qq = q - 75;
            uint2 w = make_uint2(0u, 0u);
            if (valid) {
                float4 v = ((const float4*)(out + (long)(prevOff + 2 * (node0 + j) + 1) * H))[qq];
                w = pack4(v);
            }
            *(uint2*)(rowb + 608 + qq * 8) = w;
        } else {
            int pb = (q == 150) ? 600 : (1208 + (q - 151) * 8);
            *(uint2*)(rowb + pb) = make_uint2(0u, 0u);
        }
    }
    __syncthreads();

    int wv = tid >> 6, lane = tid & 63;
    int colT0 = cb * 80;
    f32x4 acc[5];
    #pragma unroll
    for (int t = 0; t < 5; ++t) acc[t] = (f32x4)(0.f);
    if (wv == 0)      mfma_gemm<5, 5, 616, 608>(Abf,       WArz,       colT0, lane, acc);
    else if (wv == 1) mfma_gemm<5, 5, 616, 608>(Abf + 160, WArz + 160, colT0, lane, acc);
    else if (wv == 2) mfma_gemm<5, 5, 616, 608>(Abf + 320, WArz + 320, colT0, lane, acc);
    else              mfma_gemm<5, 4, 616, 608>(Abf + 480, WArz + 480, colT0, lane, acc);
    if (wv > 0) {
        #pragma unroll
        for (int t = 0; t < 5; ++t)
            #pragma unroll
            for (int q = 0; q < 4; ++q)
                pbuf[wv - 1][lane][t * 4 + q] = acc[t][q];
    }
    __syncthreads();
    if (wv == 0) {
        int jrow = (lane >> 4) * 4;
        #pragma unroll
        for (int t = 0; t < 5; ++t) {
            int c = colT0 + t * 16 + (lane & 15);
            #pragma unroll
            for (int q = 0; q < 4; ++q) {
                int jn = jrow + q, gn = node0 + jn;
                float a = acc[t][q] + pbuf[0][lane][t * 4 + q]
                        + pbuf[1][lane][t * 4 + q] + pbuf[2][lane][t * 4 + q];
                if (c < 320) {                      // r gate
                    if (c < 300 && gn < m) {
                        int tg = tag_ids[off + gn];
                        float r  = sigmoidf_(a + tag_r[tg * H + c]);
                        float lh = out[(long)(prevOff + 2 * gn) * H + c];
                        float rh = out[(long)(prevOff + 2 * gn + 1) * H + c];
                        Sws[gn * 304 + c] = lh + rh;
                        rxws[(long)gn * 608 + c]       = f2bf(r * lh);
                        rxws[(long)gn * 608 + 304 + c] = f2bf(r * rh);
                    } else if (c >= 300 && c < 304 && gn < m) {
                        rxws[(long)gn * 608 + c]       = 0;
                        rxws[(long)gn * 608 + 304 + c] = 0;
                    }
                } else {                            // z gate
                    int cz = c - 320;
                    if (cz < 300 && gn < m) {
                        int tg = tag_ids[off + gn];
                        zws[gn * 304 + cz] = sigmoidf_(a + tag_z[tg * H + cz]);
                    }
                }
            }
        }
    }
}

__global__ __launch_bounds__(256, 1) void split_u_k(
    const ushort* __restrict__ WuTp, const float* __restrict__ bu,
    const float* __restrict__ zws, const float* __restrict__ Sws,
    const ushort* __restrict__ rxws,
    float* __restrict__ out, int off, int m, float* __restrict__ dup)
{
    __shared__ ushort Abf[16 * 616];
    __shared__ float pbuf[3][64][20];
    int tid = threadIdx.x;
    int mt = blockIdx.x >> 2, ub = blockIdx.x & 3;
    int node0 = mt * 16;

    for (int idx = tid; idx < 16 * 77; idx += 256) {
        int j = idx / 77, q = idx - j * 77;
        uint4* dst = (uint4*)(Abf + j * 616) + q;
        if (q < 76 && (node0 + j) < m)
            *dst = ((const uint4*)(rxws + (long)(node0 + j) * 608))[q];
        else
            *dst = make_uint4(0u, 0u, 0u, 0u);
    }
    __syncthreads();

    int wv = tid >> 6, lane = tid & 63;
    int colT0 = ub * 80;
    f32x4 acc[5];
    #pragma unroll
    for (int t = 0; t < 5; ++t) acc[t] = (f32x4)(0.f);
    if (wv == 0)      mfma_gemm<5, 5, 616, 608>(Abf,       WuTp,       colT0, lane, acc);
    else if (wv == 1) mfma_gemm<5, 5, 616, 608>(Abf + 160, WuTp + 160, colT0, lane, acc);
    else if (wv == 2) mfma_gemm<5, 5, 616, 608>(Abf + 320, WuTp + 320, colT0, lane, acc);
    else              mfma_gemm<5, 4, 616, 608>(Abf + 480, WuTp + 480, colT0, lane, acc);
    if (wv > 0) {
        #pragma unroll
        for (int t = 0; t < 5; ++t)
            #pragma unroll
            for (int q = 0; q < 4; ++q)
                pbuf[wv - 1][lane][t * 4 + q] = acc[t][q];
    }
    __syncthreads();
    if (wv == 0) {
        int jrow = (lane >> 4) * 4;
        #pragma unroll
        for (int t = 0; t < 5; ++t) {
            int c = colT0 + t * 16 + (lane & 15);
            #pragma unroll
            for (int q = 0; q < 4; ++q) {
                int jn = jrow + q, gn = node0 + jn;
                if (c < 300 && gn < m) {
                    float a = acc[t][q] + pbuf[0][lane][t * 4 + q]
                            + pbuf[1][lane][t * 4 + q] + pbuf[2][lane][t * 4 + q];
                    float u = tanhf(a + bu[c]);
                    float z = zws[gn * 304 + c];
                    float h = z * Sws[gn * 304 + c] + (1.f - z) * u;
                    out[(long)(off + gn) * H + c] = h;
                    if (dup && gn == 0) dup[c] = h;
                }
            }
        }
    }
}

extern "C" void kernel_launch(void* const* d_in, const int* in_sizes, int n_in,
                              void* d_out, int out_size, void* d_ws, size_t ws_size,
                              hipStream_t stream)
{
    const int*   word_ids   = (const int*)  d_in[0];
    const int*   tag_ids    = (const int*)  d_in[1];
    const float* word_table = (const float*)d_in[2];
    const float* tag_table  = (const float*)d_in[3];
    const float* Wr         = (const float*)d_in[4];
    const float* br         = (const float*)d_in[5];
    const float* Wz         = (const float*)d_in[6];
    const float* bz         = (const float*)d_in[7];
    const float* Wu         = (const float*)d_in[8];
    const float* bu         = (const float*)d_in[9];
    float* out = (float*)d_out;

    float* tag_r = (float*)d_ws;                  // 18000 f32
    float* tag_z = tag_r + 18000;                 // 18000 f32
    float* zws   = tag_z + 18000;                 // 2048*304 f32
    float* Sws   = zws + 2048 * 304;              // 2048*304 f32
    ushort* rxws = (ushort*)(Sws + 2048 * 304);   // 2048*608 bf16
    ushort* WArz = rxws + 2048L * 608;            // 640*608 bf16
    ushort* WuTp = WArz + 640L * 608;             // 320*608
    ushort* WLzu = WuTp + 320L * 608;             // 640*320

    prep_k<<<700, 256, 0, stream>>>(Wr, Wz, Wu, tag_table, br, bz,
                                    WArz, WuTp, WLzu, tag_r, tag_z);

    leaf32_k<<<(NLEAF / 32) * 4, 256, 0, stream>>>(
        word_ids, tag_ids, word_table, WLzu, bu, tag_z, out);

    float* finalDup = out + (long)8191 * H;
    int off = NLEAF, prevOff = 0;
    for (int m = 2048; m >= 1; m >>= 1) {
        if (m >= 256) {
            glevel32_k<<<(m / 32) * 8, 256, 0, stream>>>(
                tag_ids, WArz, tag_r, tag_z, out, zws, Sws, rxws, off, prevOff);
            ulevel32_k<<<(m / 32) * 4, 256, 0, stream>>>(
                WuTp, bu, zws, Sws, rxws, out, off);
        } else {
            int nMt = (m + 15) / 16;
            split_gates_k<<<nMt * 8, 256, 0, stream>>>(
                tag_ids, WArz, tag_r, tag_z, out, zws, Sws, rxws, off, prevOff, m);
            split_u_k<<<nMt * 4, 256, 0, stream>>>(
                WuTp, bu, zws, Sws, rxws, out, off, m, (m == 1) ? finalDup : nullptr);
        }
        prevOff = off;
        off += m;
    }
}

// Round 22
// 313.898 us; speedup vs baseline: 1.2363x; 1.2363x over previous
//
#include <hip/hip_runtime.h>
#include <math.h>

#define H 300
#define NLEAF 4096

typedef unsigned int  uint;
typedef unsigned short ushort;
typedef __attribute__((ext_vector_type(8))) short  short8;
typedef __attribute__((ext_vector_type(4))) float  f32x4;

__device__ __forceinline__ float sigmoidf_(float x) { return 1.0f / (1.0f + expf(-x)); }

__device__ __forceinline__ ushort f2bf(float f)
{
    uint u = __float_as_uint(f);
    u += 0x7FFF + ((u >> 16) & 1);
    return (ushort)(u >> 16);
}
__device__ __forceinline__ uint2 pack4(float4 v)
{
    uint2 w;
    w.x = (uint)f2bf(v.x) | ((uint)f2bf(v.y) << 16);
    w.y = (uint)f2bf(v.z) | ((uint)f2bf(v.w) << 16);
    return w;
}

// ---- per-wave MFMA GEMM over FRAGMENT-TILED B ----
// B tiled as [colTile][kstep][512 ushorts]: fragment (tile,s) is contiguous
// 1024B; lane l reads its short8 at frag + l*8 — fully coalesced (16B/lane).
// A in LDS (row stride AS ushorts): row=lane%16, k=(s0+s)*32+(lane>>4)*8+i.
// C/D col=lane&15, row=(lane>>4)*4+reg (m89-verified).
// KT = total ksteps in the tiled tensor; s0 = kstep start offset.
template<int NT, int KSTEPS, int KT, int AS>
__device__ __forceinline__ void mfma_gemm(const ushort* A_lds, const ushort* __restrict__ Bt,
                                          int tile0, int s0, int lane, f32x4* acc)
{
    const ushort* Ap = A_lds + (lane & 15) * AS + ((lane >> 4) * 8) + s0 * 32;
    const ushort* Bp[NT];
    #pragma unroll
    for (int t = 0; t < NT; ++t)
        Bp[t] = Bt + ((long)(tile0 + t) * KT + s0) * 512 + lane * 8;

    short8 aA, aB, bA[NT], bB[NT];
    aA = *(const short8*)Ap;
    #pragma unroll
    for (int t = 0; t < NT; ++t) bA[t] = *(const short8*)Bp[t];

    int s = 0;
    #pragma unroll 1
    for (; s + 2 < KSTEPS; s += 2) {
        aB = *(const short8*)(Ap + (s + 1) * 32);
        #pragma unroll
        for (int t = 0; t < NT; ++t) bB[t] = *(const short8*)(Bp[t] + (s + 1) * 512);
        #pragma unroll
        for (int t = 0; t < NT; ++t)
            acc[t] = __builtin_amdgcn_mfma_f32_16x16x32_bf16(aA, bA[t], acc[t], 0, 0, 0);
        aA = *(const short8*)(Ap + (s + 2) * 32);
        #pragma unroll
        for (int t = 0; t < NT; ++t) bA[t] = *(const short8*)(Bp[t] + (s + 2) * 512);
        #pragma unroll
        for (int t = 0; t < NT; ++t)
            acc[t] = __builtin_amdgcn_mfma_f32_16x16x32_bf16(aB, bB[t], acc[t], 0, 0, 0);
    }
    if (KSTEPS - s == 2) {
        aB = *(const short8*)(Ap + (s + 1) * 32);
        #pragma unroll
        for (int t = 0; t < NT; ++t) bB[t] = *(const short8*)(Bp[t] + (s + 1) * 512);
        #pragma unroll
        for (int t = 0; t < NT; ++t)
            acc[t] = __builtin_amdgcn_mfma_f32_16x16x32_bf16(aA, bA[t], acc[t], 0, 0, 0);
        #pragma unroll
        for (int t = 0; t < NT; ++t)
            acc[t] = __builtin_amdgcn_mfma_f32_16x16x32_bf16(aB, bB[t], acc[t], 0, 0, 0);
    } else {
        #pragma unroll
        for (int t = 0; t < NT; ++t)
            acc[t] = __builtin_amdgcn_mfma_f32_16x16x32_bf16(aA, bA[t], acc[t], 0, 0, 0);
    }
}

// ---- merged prep: tiled-bf16 weight build (blocks 0-639) + tag tables (640-699)
// WArzT: 40 tiles x 19 ksteps x 512  (cols 0-299 r slice, 320-619 z slice)
// WuTpT: 20 tiles x 19 ksteps x 512  (u slice)
// WLzuT: 40 tiles x 10 ksteps x 512  (cols 0-299 leaf-z, 320-619 leaf-u)
__global__ __launch_bounds__(256) void prep_k(
    const float* __restrict__ Wr, const float* __restrict__ Wz,
    const float* __restrict__ Wu, const float* __restrict__ tag_table,
    const float* __restrict__ br, const float* __restrict__ bz,
    ushort* __restrict__ WArzT, ushort* __restrict__ WuTpT, ushort* __restrict__ WLzuT,
    float* __restrict__ tag_r, float* __restrict__ tag_z)
{
    __shared__ float te[50];
    int b = blockIdx.x;
    int tid = threadIdx.x;
    if (b < 640) {
        int c = b;
        int tile = c >> 4, cl = c & 15;
        int gate = (c >= 320);
        int cc = gate ? c - 320 : c;
        const float* WA = gate ? Wz : Wr;
        for (int o = tid; o < 76; o += 256) {          // WArzT octets (K=608)
            int k0 = o * 8;
            ushort tmp[8];
            #pragma unroll
            for (int i = 0; i < 8; ++i) {
                int k = k0 + i;
                float v = 0.f;
                if (cc < 300) {
                    if (k < 300) v = WA[(350 + k) * H + cc];
                    else if (k >= 304 && k < 604) v = WA[(k + 346) * H + cc];
                }
                tmp[i] = f2bf(v);
            }
            int s = k0 >> 5, kk0 = k0 & 31;
            long pos = ((long)(tile * 19 + s)) * 512 + ((kk0 >> 3) * 16 + cl) * 8;
            uint4 w;
            w.x = (uint)tmp[0] | ((uint)tmp[1] << 16);
            w.y = (uint)tmp[2] | ((uint)tmp[3] << 16);
            w.z = (uint)tmp[4] | ((uint)tmp[5] << 16);
            w.w = (uint)tmp[6] | ((uint)tmp[7] << 16);
            *(uint4*)&WArzT[pos] = w;
        }
        const float* WL = gate ? Wu : Wz;
        for (int o = tid; o < 40; o += 256) {          // WLzuT octets (K=320)
            int k0 = o * 8;
            ushort tmp[8];
            #pragma unroll
            for (int i = 0; i < 8; ++i) {
                int k = k0 + i;
                float v = (cc < 300 && k < 300) ? WL[k * H + cc] : 0.f;
                tmp[i] = f2bf(v);
            }
            int s = k0 >> 5, kk0 = k0 & 31;
            long pos = ((long)(tile * 10 + s)) * 512 + ((kk0 >> 3) * 16 + cl) * 8;
            uint4 w;
            w.x = (uint)tmp[0] | ((uint)tmp[1] << 16);
            w.y = (uint)tmp[2] | ((uint)tmp[3] << 16);
            w.z = (uint)tmp[4] | ((uint)tmp[5] << 16);
            w.w = (uint)tmp[6] | ((uint)tmp[7] << 16);
            *(uint4*)&WLzuT[pos] = w;
        }
        if (c < 320) {
            for (int o = tid; o < 76; o += 256) {      // WuTpT octets (K=608)
                int k0 = o * 8;
                ushort tmp[8];
                #pragma unroll
                for (int i = 0; i < 8; ++i) {
                    int k = k0 + i;
                    float v = 0.f;
                    if (c < 300) {
                        if (k < 300) v = Wu[(300 + k) * H + c];
                        else if (k >= 304 && k < 604) v = Wu[(k + 296) * H + c];
                    }
                    tmp[i] = f2bf(v);
                }
                int s = k0 >> 5, kk0 = k0 & 31;
                long pos = ((long)(tile * 19 + s)) * 512 + ((kk0 >> 3) * 16 + cl) * 8;
                uint4 w;
                w.x = (uint)tmp[0] | ((uint)tmp[1] << 16);
                w.y = (uint)tmp[2] | ((uint)tmp[3] << 16);
                w.z = (uint)tmp[4] | ((uint)tmp[5] << 16);
                w.w = (uint)tmp[6] | ((uint)tmp[7] << 16);
                *(uint4*)&WuTpT[pos] = w;
            }
        }
    } else {
        int t = b - 640;                 // 0..59
        if (tid < 50) te[tid] = tag_table[t * 50 + tid];
        __syncthreads();
        for (int k = tid; k < H; k += 256) {
            float ar = br[k], az = bz[k];
            #pragma unroll 10
            for (int j = 0; j < 50; ++j) {
                float tv = te[j];
                ar = fmaf(tv, Wr[(H + j) * H + k], ar);
                az = fmaf(tv, Wz[(H + j) * H + k], az);
            }
            tag_r[t * H + k] = ar;
            tag_z[t * H + k] = az;
        }
    }
}

// ---- Leaf (MFMA, 512 thr / 8 waves): waves 0-3 z-cols, waves 4-7 u-cols.
__global__ __launch_bounds__(512, 1) void leaf_mfma_k(
    const int* __restrict__ word_ids, const int* __restrict__ tag_ids,
    const float* __restrict__ word_table, const ushort* __restrict__ WLzuT,
    const float* __restrict__ bu, const float* __restrict__ tag_z,
    float* __restrict__ out)
{
    __shared__ ushort Abf[16 * 328];
    __shared__ float zbuf[16][304];
    int tid = threadIdx.x;
    int node0 = blockIdx.x * 16;

    for (int idx = tid; idx < 16 * 82; idx += 512) {
        int j = idx / 82, q = idx - j * 82;
        char* rowb = (char*)(Abf + j * 328);
        if (q < 75) {
            float4 v = ((const float4*)(word_table + (long)word_ids[node0 + j] * H))[q];
            *(uint2*)(rowb + q * 8) = pack4(v);
        } else {
            *(uint2*)(rowb + q * 8) = make_uint2(0u, 0u);
        }
    }
    __syncthreads();

    int wv = tid >> 6, lane = tid & 63;
    int jrow = (lane >> 4) * 4;

    f32x4 acc[5];
    #pragma unroll
    for (int t = 0; t < 5; ++t) acc[t] = (f32x4)(0.f);

    if (wv < 4) {
        mfma_gemm<5, 10, 10, 328>(Abf, WLzuT, wv * 5, 0, lane, acc);
        int tg[4];
        #pragma unroll
        for (int q = 0; q < 4; ++q) tg[q] = tag_ids[node0 + jrow + q];
        #pragma unroll
        for (int t = 0; t < 5; ++t) {
            int c = wv * 80 + t * 16 + (lane & 15);
            #pragma unroll
            for (int q = 0; q < 4; ++q)
                if (c < 300) zbuf[jrow + q][c] = sigmoidf_(acc[t][q] + tag_z[tg[q] * H + c]);
        }
    } else {
        mfma_gemm<5, 10, 10, 328>(Abf, WLzuT, 20 + (wv - 4) * 5, 0, lane, acc);
    }
    __syncthreads();
    if (wv >= 4) {
        #pragma unroll
        for (int t = 0; t < 5; ++t) {
            int c = (wv - 4) * 80 + t * 16 + (lane & 15);
            #pragma unroll
            for (int q = 0; q < 4; ++q) {
                if (c < 300) {
                    int jn = jrow + q;
                    float u = tanhf(acc[t][q] + bu[c]);
                    out[(long)(node0 + jn) * H + c] = (1.f - zbuf[jn][c]) * u;
                }
            }
        }
    }
}

// ---- Fused internal level (512 thr / 8 waves, 16 nodes), for m >= 256 ----
__device__ __forceinline__ void fused_body(
    const int* __restrict__ tag_ids, const ushort* __restrict__ WArzT,
    const ushort* __restrict__ WuTpT, const float* __restrict__ bu,
    const float* __restrict__ tag_r, const float* __restrict__ tag_z,
    float* __restrict__ out, int off, int prevOff, int m,
    int node0, int tid, ushort* Abf, float (*zbuf)[304], float (*pbuf)[64][21])
{
    for (int idx = tid; idx < 16 * 154; idx += 512) {
        int j = idx / 154, q = idx - j * 154;
        char* rowb = (char*)(Abf + j * 616);
        bool valid = (node0 + j) < m;
        if (q < 75) {
            uint2 w = make_uint2(0u, 0u);
            if (valid) {
                float4 v = ((const float4*)(out + (long)(prevOff + 2 * (node0 + j)) * H))[q];
                w = pack4(v);
            }
            *(uint2*)(rowb + q * 8) = w;
        } else if (q < 150) {
            int qq = q - 75;
            uint2 w = make_uint2(0u, 0u);
            if (valid) {
                float4 v = ((const float4*)(out + (long)(prevOff + 2 * (node0 + j) + 1) * H))[qq];
                w = pack4(v);
            }
            *(uint2*)(rowb + 608 + qq * 8) = w;
        } else {
            int pb = (q == 150) ? 600 : (1208 + (q - 151) * 8);
            *(uint2*)(rowb + pb) = make_uint2(0u, 0u);
        }
    }
    __syncthreads();

    int wv = tid >> 6, lane = tid & 63;
    int jrow = (lane >> 4) * 4;
    int tg[4];
    #pragma unroll
    for (int q = 0; q < 4; ++q) {
        int gn = node0 + jrow + q;
        tg[q] = tag_ids[off + (gn < m ? gn : 0)];
    }

    f32x4 accG[5];
    #pragma unroll
    for (int t = 0; t < 5; ++t) accG[t] = (f32x4)(0.f);
    mfma_gemm<5, 19, 19, 616>(Abf, WArzT, wv * 5, 0, lane, accG);
    __syncthreads();

    float Sr[5][4];
    if (wv < 4) {
        #pragma unroll
        for (int t = 0; t < 5; ++t) {
            int c = wv * 80 + t * 16 + (lane & 15);
            #pragma unroll
            for (int q = 0; q < 4; ++q) {
                int jn = jrow + q, gn = node0 + jn;
                if (c < 300 && gn < m) {
                    float lh = out[(long)(prevOff + 2 * gn) * H + c];
                    float rh = out[(long)(prevOff + 2 * gn + 1) * H + c];
                    float r  = sigmoidf_(accG[t][q] + tag_r[tg[q] * H + c]);
                    Sr[t][q] = lh + rh;
                    Abf[jn * 616 + c]       = f2bf(r * lh);
                    Abf[jn * 616 + 304 + c] = f2bf(r * rh);
                }
            }
        }
    } else {
        #pragma unroll
        for (int t = 0; t < 5; ++t) {
            int cz = (wv - 4) * 80 + t * 16 + (lane & 15);
            #pragma unroll
            for (int q = 0; q < 4; ++q) {
                int jn = jrow + q, gn = node0 + jn;
                if (cz < 300 && gn < m)
                    zbuf[jn][cz] = sigmoidf_(accG[t][q] + tag_z[tg[q] * H + cz]);
            }
        }
    }
    __syncthreads();

    f32x4 accU[5];
    #pragma unroll
    for (int t = 0; t < 5; ++t) accU[t] = (f32x4)(0.f);
    if (wv < 4) {
        mfma_gemm<5, 10, 19, 616>(Abf, WuTpT, wv * 5, 0, lane, accU);
    } else {
        mfma_gemm<5, 9, 19, 616>(Abf, WuTpT, (wv - 4) * 5, 10, lane, accU);
        #pragma unroll
        for (int t = 0; t < 5; ++t)
            #pragma unroll
            for (int q = 0; q < 4; ++q)
                pbuf[wv - 4][lane][t * 4 + q] = accU[t][q];
    }
    __syncthreads();
    if (wv < 4) {
        #pragma unroll
        for (int t = 0; t < 5; ++t) {
            int c = wv * 80 + t * 16 + (lane & 15);
            #pragma unroll
            for (int q = 0; q < 4; ++q) {
                int jn = jrow + q, gn = node0 + jn;
                if (c < 300 && gn < m) {
                    float a = accU[t][q] + pbuf[wv][lane][t * 4 + q];
                    float u = tanhf(a + bu[c]);
                    float z = zbuf[jn][c];
                    out[(long)(off + gn) * H + c] = z * Sr[t][q] + (1.f - z) * u;
                }
            }
        }
    }
}

__global__ __launch_bounds__(512, 1) void level_fused_k(
    const int* __restrict__ tag_ids, const ushort* __restrict__ WArzT,
    const ushort* __restrict__ WuTpT, const float* __restrict__ bu,
    const float* __restrict__ tag_r, const float* __restrict__ tag_z,
    float* __restrict__ out, int off, int prevOff, int m)
{
    __shared__ ushort Abf[16 * 616];
    __shared__ float zbuf[16][304];
    __shared__ float pbuf[4][64][21];
    fused_body(tag_ids, WArzT, WuTpT, bu, tag_r, tag_z, out, off, prevOff, m,
               blockIdx.x * 16, threadIdx.x, Abf, zbuf, pbuf);
}

// ---- Small levels (m <= 128): per-level 2-kernel column+K-split ----
__global__ __launch_bounds__(256, 1) void split_gates_k(
    const int* __restrict__ tag_ids, const ushort* __restrict__ WArzT,
    const float* __restrict__ tag_r, const float* __restrict__ tag_z,
    const float* __restrict__ out,
    float* __restrict__ zws, float* __restrict__ Sws, ushort* __restrict__ rxws,
    int off, int prevOff, int m)
{
    __shared__ ushort Abf[16 * 616];
    __shared__ float pbuf[3][64][20];
    int tid = threadIdx.x;
    int mt = blockIdx.x >> 3, cb = blockIdx.x & 7;
    int node0 = mt * 16;

    for (int idx = tid; idx < 16 * 154; idx += 256) {
        int j = idx / 154, q = idx - j * 154;
        char* rowb = (char*)(Abf + j * 616);
        bool valid = (node0 + j) < m;
        if (q < 75) {
            uint2 w = make_uint2(0u, 0u);
            if (valid) {
                float4 v = ((const float4*)(out + (long)(prevOff + 2 * (node0 + j)) * H))[q];
                w = pack4(v);
            }
            *(uint2*)(rowb + q * 8) = w;
        } else if (q < 150) {
            int qq = q - 75;
            uint2 w = make_uint2(0u, 0u);
            if (valid) {
                float4 v = ((const float4*)(out + (long)(prevOff + 2 * (node0 + j) + 1) * H))[qq];
                w = pack4(v);
            }
            *(uint2*)(rowb + 608 + qq * 8) = w;
        } else {
            int pb = (q == 150) ? 600 : (1208 + (q - 151) * 8);
            *(uint2*)(rowb + pb) = make_uint2(0u, 0u);
        }
    }
    __syncthreads();

    int wv = tid >> 6, lane = tid & 63;
    int tile0 = cb * 5;
    f32x4 acc[5];
    #pragma unroll
    for (int t = 0; t < 5; ++t) acc[t] = (f32x4)(0.f);
    if (wv == 0)      mfma_gemm<5, 5, 19, 616>(Abf, WArzT, tile0, 0,  lane, acc);
    else if (wv == 1) mfma_gemm<5, 5, 19, 616>(Abf, WArzT, tile0, 5,  lane, acc);
    else if (wv == 2) mfma_gemm<5, 5, 19, 616>(Abf, WArzT, tile0, 10, lane, acc);
    else              mfma_gemm<5, 4, 19, 616>(Abf, WArzT, tile0, 15, lane, acc);
    if (wv > 0) {
        #pragma unroll
        for (int t = 0; t < 5; ++t)
            #pragma unroll
            for (int q = 0; q < 4; ++q)
                pbuf[wv - 1][lane][t * 4 + q] = acc[t][q];
    }
    __syncthreads();
    if (wv == 0) {
        int jrow = (lane >> 4) * 4;
        #pragma unroll
        for (int t = 0; t < 5; ++t) {
            int c = cb * 80 + t * 16 + (lane & 15);
            #pragma unroll
            for (int q = 0; q < 4; ++q) {
                int jn = jrow + q, gn = node0 + jn;
                float a = acc[t][q] + pbuf[0][lane][t * 4 + q]
                        + pbuf[1][lane][t * 4 + q] + pbuf[2][lane][t * 4 + q];
                if (c < 320) {                      // r gate
                    if (c < 300 && gn < m) {
                        int tg = tag_ids[off + gn];
                        float r  = sigmoidf_(a + tag_r[tg * H + c]);
                        float lh = out[(long)(prevOff + 2 * gn) * H + c];
                        float rh = out[(long)(prevOff + 2 * gn + 1) * H + c];
                        Sws[gn * 304 + c] = lh + rh;
                        rxws[(long)gn * 608 + c]       = f2bf(r * lh);
                        rxws[(long)gn * 608 + 304 + c] = f2bf(r * rh);
                    } else if (c >= 300 && c < 304 && gn < m) {
                        rxws[(long)gn * 608 + c]       = 0;
                        rxws[(long)gn * 608 + 304 + c] = 0;
                    }
                } else {                            // z gate
                    int cz = c - 320;
                    if (cz < 300 && gn < m) {
                        int tg = tag_ids[off + gn];
                        zws[gn * 304 + cz] = sigmoidf_(a + tag_z[tg * H + cz]);
                    }
                }
            }
        }
    }
}

__global__ __launch_bounds__(256, 1) void split_u_k(
    const ushort* __restrict__ WuTpT, const float* __restrict__ bu,
    const float* __restrict__ zws, const float* __restrict__ Sws,
    const ushort* __restrict__ rxws,
    float* __restrict__ out, int off, int m, float* __restrict__ dup)
{
    __shared__ ushort Abf[16 * 616];
    __shared__ float pbuf[3][64][20];
    int tid = threadIdx.x;
    int mt = blockIdx.x >> 2, ub = blockIdx.x & 3;
    int node0 = mt * 16;

    for (int idx = tid; idx < 16 * 77; idx += 256) {
        int j = idx / 77, q = idx - j * 77;
        uint4* dst = (uint4*)(Abf + j * 616) + q;
        if (q < 76 && (node0 + j) < m)
            *dst = ((const uint4*)(rxws + (long)(node0 + j) * 608))[q];
        else
            *dst = make_uint4(0u, 0u, 0u, 0u);
    }
    __syncthreads();

    int wv = tid >> 6, lane = tid & 63;
    int tile0 = ub * 5;
    f32x4 acc[5];
    #pragma unroll
    for (int t = 0; t < 5; ++t) acc[t] = (f32x4)(0.f);
    if (wv == 0)      mfma_gemm<5, 5, 19, 616>(Abf, WuTpT, tile0, 0,  lane, acc);
    else if (wv == 1) mfma_gemm<5, 5, 19, 616>(Abf, WuTpT, tile0, 5,  lane, acc);
    else if (wv == 2) mfma_gemm<5, 5, 19, 616>(Abf, WuTpT, tile0, 10, lane, acc);
    else              mfma_gemm<5, 4, 19, 616>(Abf, WuTpT, tile0, 15, lane, acc);
    if (wv > 0) {
        #pragma unroll
        for (int t = 0; t < 5; ++t)
            #pragma unroll
            for (int q = 0; q < 4; ++q)
                pbuf[wv - 1][lane][t * 4 + q] = acc[t][q];
    }
    __syncthreads();
    if (wv == 0) {
        int jrow = (lane >> 4) * 4;
        #pragma unroll
        for (int t = 0; t < 5; ++t) {
            int c = ub * 80 + t * 16 + (lane & 15);
            #pragma unroll
            for (int q = 0; q < 4; ++q) {
                int jn = jrow + q, gn = node0 + jn;
                if (c < 300 && gn < m) {
                    float a = acc[t][q] + pbuf[0][lane][t * 4 + q]
                            + pbuf[1][lane][t * 4 + q] + pbuf[2][lane][t * 4 + q];
                    float u = tanhf(a + bu[c]);
                    float z = zws[gn * 304 + c];
                    float h = z * Sws[gn * 304 + c] + (1.f - z) * u;
                    out[(long)(off + gn) * H + c] = h;
                    if (dup && gn == 0) dup[c] = h;
                }
            }
        }
    }
}

extern "C" void kernel_launch(void* const* d_in, const int* in_sizes, int n_in,
                              void* d_out, int out_size, void* d_ws, size_t ws_size,
                              hipStream_t stream)
{
    const int*   word_ids   = (const int*)  d_in[0];
    const int*   tag_ids    = (const int*)  d_in[1];
    const float* word_table = (const float*)d_in[2];
    const float* tag_table  = (const float*)d_in[3];
    const float* Wr         = (const float*)d_in[4];
    const float* br         = (const float*)d_in[5];
    const float* Wz         = (const float*)d_in[6];
    const float* bz         = (const float*)d_in[7];
    const float* Wu         = (const float*)d_in[8];
    const float* bu         = (const float*)d_in[9];
    float* out = (float*)d_out;

    float* tag_r = (float*)d_ws;                  // 18000 f32
    float* tag_z = tag_r + 18000;                 // 18000 f32
    float* zws   = tag_z + 18000;                 // 128*304 f32
    float* Sws   = zws + 128 * 304;               // 128*304 f32
    ushort* rxws = (ushort*)(Sws + 128 * 304);    // 128*608 bf16
    ushort* WArzT = rxws + 128L * 608;            // 40*19*512 = 389120 bf16
    ushort* WuTpT = WArzT + 40L * 19 * 512;       // 20*19*512 = 194560
    ushort* WLzuT = WuTpT + 20L * 19 * 512;       // 40*10*512 = 204800

    prep_k<<<700, 256, 0, stream>>>(Wr, Wz, Wu, tag_table, br, bz,
                                    WArzT, WuTpT, WLzuT, tag_r, tag_z);

    leaf_mfma_k<<<NLEAF / 16, 512, 0, stream>>>(
        word_ids, tag_ids, word_table, WLzuT, bu, tag_z, out);

    float* finalDup = out + (long)8191 * H;
    int off = NLEAF, prevOff = 0;
    for (int m = 2048; m >= 1; m >>= 1) {
        if (m >= 256) {
            level_fused_k<<<m / 16, 512, 0, stream>>>(
                tag_ids, WArzT, WuTpT, bu, tag_r, tag_z, out, off, prevOff, m);
        } else {
            int nMt = (m + 15) / 16;
            split_gates_k<<<nMt * 8, 256, 0, stream>>>(
                tag_ids, WArzT, tag_r, tag_z, out, zws, Sws, rxws, off, prevOff, m);
            split_u_k<<<nMt * 4, 256, 0, stream>>>(
                WuTpT, bu, zws, Sws, rxws, out, off, m, (m == 1) ? finalDup : nullptr);
        }
        prevOff = off;
        off += m;
    }
}